// Round 1
// baseline (533.922 us; speedup 1.0000x reference)
//
#include <hip/hip_runtime.h>

typedef unsigned short u16;
typedef __attribute__((ext_vector_type(8))) short short8;
typedef __attribute__((ext_vector_type(4))) float f32x4;

#define D_MODEL 1024
#define SEQ 2048
#define NH 16
#define DK 64
#define DFF 4096
#define NTOK 4096

__device__ __forceinline__ u16 f2bf(float f) {
    unsigned x = __builtin_bit_cast(unsigned, f);
    x = x + 0x7fffu + ((x >> 16) & 1u);
    return (u16)(x >> 16);
}

// ---------------- fp32 -> bf16 convert ----------------
__global__ __launch_bounds__(256) void cvt_bf16(const float* __restrict__ in,
                                                u16* __restrict__ out) {
    size_t i = ((size_t)blockIdx.x * 256 + threadIdx.x) * 4;
    float4 v = *(const float4*)(in + i);
    out[i + 0] = f2bf(v.x);
    out[i + 1] = f2bf(v.y);
    out[i + 2] = f2bf(v.z);
    out[i + 3] = f2bf(v.w);
}

// ---------------- generic GEMM: C[M,N] = A[M,K](bf16) @ W[N,K](fp32)^T + bias ----------------
// EPI 0: fp32 out, row-major [M][N]
// EPI 1: bf16 out, relu, row-major [M][N]
// EPI 2: bf16 out, scaled, QKV head layout [B,H,S,dk]
template <int EPI>
__global__ __launch_bounds__(256) void gemm_bt(
    const u16* __restrict__ A, const float* __restrict__ W,
    const float* __restrict__ bias, u16* __restrict__ outb,
    float* __restrict__ outf, int M, int N, int K, float scale) {
    __shared__ short8 As[128][5];  // [row][kgroup], 16B-aligned elements, pad col
    __shared__ short8 Bs[128][5];  // [col][kgroup]

    const int tid = threadIdx.x;
    const int lane = tid & 63;
    const int w = tid >> 6;
    const int wr = (w >> 1) * 64;
    const int wc = (w & 1) * 64;
    const int l15 = lane & 15;
    const int lg = lane >> 4;
    const int m0 = blockIdx.y * 128;
    const int n0 = blockIdx.x * 128;

    f32x4 zero = {0.f, 0.f, 0.f, 0.f};
    f32x4 acc[4][4];
#pragma unroll
    for (int i = 0; i < 4; ++i)
#pragma unroll
        for (int j = 0; j < 4; ++j) acc[i][j] = zero;

    const int ar0 = tid >> 2, ag0 = tid & 3;
    const int ar1 = (256 + tid) >> 2, ag1 = (256 + tid) & 3;

    for (int k0 = 0; k0 < K; k0 += 32) {
        __syncthreads();
        // stage A (bf16 direct)
        As[ar0][ag0] = *(const short8*)(A + (size_t)(m0 + ar0) * K + k0 + ag0 * 8);
        As[ar1][ag1] = *(const short8*)(A + (size_t)(m0 + ar1) * K + k0 + ag1 * 8);
        // stage B (fp32 -> bf16)
        {
            const float* s0 = W + (size_t)(n0 + ar0) * K + k0 + ag0 * 8;
            float4 f0 = *(const float4*)s0;
            float4 f1 = *(const float4*)(s0 + 4);
            short8 v;
            v[0] = (short)f2bf(f0.x); v[1] = (short)f2bf(f0.y);
            v[2] = (short)f2bf(f0.z); v[3] = (short)f2bf(f0.w);
            v[4] = (short)f2bf(f1.x); v[5] = (short)f2bf(f1.y);
            v[6] = (short)f2bf(f1.z); v[7] = (short)f2bf(f1.w);
            Bs[ar0][ag0] = v;
            const float* s1 = W + (size_t)(n0 + ar1) * K + k0 + ag1 * 8;
            float4 f2 = *(const float4*)s1;
            float4 f3 = *(const float4*)(s1 + 4);
            short8 u;
            u[0] = (short)f2bf(f2.x); u[1] = (short)f2bf(f2.y);
            u[2] = (short)f2bf(f2.z); u[3] = (short)f2bf(f2.w);
            u[4] = (short)f2bf(f3.x); u[5] = (short)f2bf(f3.y);
            u[6] = (short)f2bf(f3.z); u[7] = (short)f2bf(f3.w);
            Bs[ar1][ag1] = u;
        }
        __syncthreads();

        short8 af[4], bfr[4];
#pragma unroll
        for (int m = 0; m < 4; ++m) af[m] = As[wr + m * 16 + l15][lg];
#pragma unroll
        for (int n = 0; n < 4; ++n) bfr[n] = Bs[wc + n * 16 + l15][lg];
#pragma unroll
        for (int m = 0; m < 4; ++m)
#pragma unroll
            for (int n = 0; n < 4; ++n)
                acc[m][n] = __builtin_amdgcn_mfma_f32_16x16x32_bf16(
                    af[m], bfr[n], acc[m][n], 0, 0, 0);
    }

#pragma unroll
    for (int m = 0; m < 4; ++m) {
#pragma unroll
        for (int n = 0; n < 4; ++n) {
#pragma unroll
            for (int r = 0; r < 4; ++r) {
                int gm = m0 + wr + m * 16 + lg * 4 + r;
                int gn = n0 + wc + n * 16 + l15;
                float v = acc[m][n][r] + bias[gn];
                if (EPI == 0) {
                    outf[(size_t)gm * N + gn] = v;
                } else if (EPI == 1) {
                    outb[(size_t)gm * N + gn] = f2bf(fmaxf(v, 0.f));
                } else {
                    v *= scale;
                    int b = gm >> 11, s = gm & 2047;
                    int h = gn >> 6, d = gn & 63;
                    outb[(((size_t)(b * NH + h)) * SEQ + s) * DK + d] = f2bf(v);
                }
            }
        }
    }
}

// ---------------- flash attention: Q,K,V [B,H,S,dk] bf16 (Q pre-scaled) -> ctx [B,S,D] bf16 ----------------
__global__ __launch_bounds__(256) void attn_fwd(const u16* __restrict__ Q,
                                                const u16* __restrict__ Kp,
                                                const u16* __restrict__ V,
                                                u16* __restrict__ ctx) {
    __shared__ short8 Vt[64][5];      // V^T tile: [d][tgroup]
    __shared__ short8 Ps[4][16][5];   // per-wave P tile: [q][tgroup]

    const int tid = threadIdx.x;
    const int lane = tid & 63;
    const int w = tid >> 6;
    const int l15 = lane & 15;
    const int lg = lane >> 4;
    const int bh = blockIdx.y;
    const int qbase = blockIdx.x * 64 + w * 16;
    const size_t base = (size_t)bh * SEQ * DK;
    const u16* Qb = Q + base;
    const u16* Kb = Kp + base;
    const u16* Vb = V + base;

    short8 qf[2];
#pragma unroll
    for (int hf = 0; hf < 2; ++hf)
        qf[hf] = *(const short8*)(Qb + (size_t)(qbase + l15) * DK + hf * 32 + lg * 8);

    f32x4 zero = {0.f, 0.f, 0.f, 0.f};
    f32x4 o[4];
#pragma unroll
    for (int db = 0; db < 4; ++db) o[db] = zero;
    float mrun[4], lrun[4];
#pragma unroll
    for (int r = 0; r < 4; ++r) { mrun[r] = -1e30f; lrun[r] = 0.f; }

    const int vtt = tid & 31, vdg = tid >> 5;
    u16* Vu = (u16*)&Vt[0][0];        // d-row stride 40 u16
    u16* Pu = (u16*)&Ps[w][0][0];     // q-row stride 40 u16

    for (int t0 = 0; t0 < SEQ; t0 += 32) {
        __syncthreads();
        {   // stage V tile transposed
            short8 vv = *(const short8*)(Vb + (size_t)(t0 + vtt) * DK + vdg * 8);
#pragma unroll
            for (int j = 0; j < 8; ++j) Vu[(vdg * 8 + j) * 40 + vtt] = (u16)vv[j];
        }
        __syncthreads();

        f32x4 sc[2];
#pragma unroll
        for (int nb = 0; nb < 2; ++nb) {
            short8 kf0 = *(const short8*)(Kb + (size_t)(t0 + nb * 16 + l15) * DK + lg * 8);
            short8 kf1 = *(const short8*)(Kb + (size_t)(t0 + nb * 16 + l15) * DK + 32 + lg * 8);
            sc[nb] = __builtin_amdgcn_mfma_f32_16x16x32_bf16(qf[0], kf0, zero, 0, 0, 0);
            sc[nb] = __builtin_amdgcn_mfma_f32_16x16x32_bf16(qf[1], kf1, sc[nb], 0, 0, 0);
        }

#pragma unroll
        for (int r = 0; r < 4; ++r) {
            float rv = fmaxf(sc[0][r], sc[1][r]);
#pragma unroll
            for (int off = 8; off; off >>= 1) rv = fmaxf(rv, __shfl_xor(rv, off));
            float mnew = fmaxf(mrun[r], rv);
            float fac = __expf(mrun[r] - mnew);
            float p0 = __expf(sc[0][r] - mnew);
            float p1 = __expf(sc[1][r] - mnew);
            float rs = p0 + p1;
#pragma unroll
            for (int off = 8; off; off >>= 1) rs += __shfl_xor(rs, off);
            lrun[r] = lrun[r] * fac + rs;
            mrun[r] = mnew;
            int q = lg * 4 + r;
            Pu[q * 40 + l15] = f2bf(p0);
            Pu[q * 40 + l15 + 16] = f2bf(p1);
#pragma unroll
            for (int db = 0; db < 4; ++db) o[db][r] *= fac;
        }

        short8 pa = Ps[w][l15][lg];
#pragma unroll
        for (int db = 0; db < 4; ++db) {
            short8 vb = Vt[db * 16 + l15][lg];
            o[db] = __builtin_amdgcn_mfma_f32_16x16x32_bf16(pa, vb, o[db], 0, 0, 0);
        }
    }

    const int b = bh >> 4, h = bh & 15;
#pragma unroll
    for (int r = 0; r < 4; ++r) {
        float inv = 1.0f / lrun[r];
        int srow = qbase + lg * 4 + r;
        size_t rowoff = ((size_t)(b * SEQ + srow)) * D_MODEL + h * DK;
#pragma unroll
        for (int db = 0; db < 4; ++db)
            ctx[rowoff + db * 16 + l15] = f2bf(o[db][r] * inv);
    }
}

// ---------------- fused residual + LayerNorm ----------------
__global__ __launch_bounds__(256) void ln_res(const float* __restrict__ X,
                                              const float* __restrict__ Y,
                                              const float* __restrict__ gamma,
                                              const float* __restrict__ beta,
                                              float* __restrict__ outf,
                                              u16* __restrict__ outb) {
    __shared__ float red[8];
    const int row = blockIdx.x, t = threadIdx.x;
    const size_t off = (size_t)row * D_MODEL + t * 4;
    float4 xv = *(const float4*)(X + off);
    float4 yv = *(const float4*)(Y + off);
    float sx = xv.x + yv.x, sy = xv.y + yv.y, sz = xv.z + yv.z, sw = xv.w + yv.w;
    float ps = sx + sy + sz + sw;
#pragma unroll
    for (int o2 = 32; o2; o2 >>= 1) ps += __shfl_xor(ps, o2);
    if ((t & 63) == 0) red[t >> 6] = ps;
    __syncthreads();
    float mu = (red[0] + red[1] + red[2] + red[3]) * (1.0f / D_MODEL);
    float d0 = sx - mu, d1 = sy - mu, d2 = sz - mu, d3 = sw - mu;
    float p2 = d0 * d0 + d1 * d1 + d2 * d2 + d3 * d3;
#pragma unroll
    for (int o2 = 32; o2; o2 >>= 1) p2 += __shfl_xor(p2, o2);
    if ((t & 63) == 0) red[4 + (t >> 6)] = p2;
    __syncthreads();
    float var = (red[4] + red[5] + red[6] + red[7]) * (1.0f / D_MODEL);
    float rstd = rsqrtf(var + 1e-5f);
    float4 gv = *(const float4*)(gamma + t * 4);
    float4 bv = *(const float4*)(beta + t * 4);
    float r0 = d0 * rstd * gv.x + bv.x;
    float r1 = d1 * rstd * gv.y + bv.y;
    float r2 = d2 * rstd * gv.z + bv.z;
    float r3 = d3 * rstd * gv.w + bv.w;
    float4 res; res.x = r0; res.y = r1; res.z = r2; res.w = r3;
    *(float4*)(outf + off) = res;
    if (outb) {
        outb[off + 0] = f2bf(r0);
        outb[off + 1] = f2bf(r1);
        outb[off + 2] = f2bf(r2);
        outb[off + 3] = f2bf(r3);
    }
}

extern "C" void kernel_launch(void* const* d_in, const int* in_sizes, int n_in,
                              void* d_out, int out_size, void* d_ws, size_t ws_size,
                              hipStream_t stream) {
    (void)in_sizes; (void)n_in; (void)out_size; (void)ws_size;
    const float* x  = (const float*)d_in[0];
    const float* Wq = (const float*)d_in[1];
    const float* bq = (const float*)d_in[2];
    const float* Wk = (const float*)d_in[3];
    const float* bk = (const float*)d_in[4];
    const float* Wv = (const float*)d_in[5];
    const float* bv = (const float*)d_in[6];
    const float* Wo = (const float*)d_in[7];
    const float* bo = (const float*)d_in[8];
    const float* W1 = (const float*)d_in[9];
    const float* b1 = (const float*)d_in[10];
    const float* W2 = (const float*)d_in[11];
    const float* b2 = (const float*)d_in[12];
    const float* g1 = (const float*)d_in[13];
    const float* be1 = (const float*)d_in[14];
    const float* g2 = (const float*)d_in[15];
    const float* be2 = (const float*)d_in[16];

    char* ws = (char*)d_ws;
    u16* xb   = (u16*)(ws);                       // 8 MB  (also reused as ctx)
    u16* Qb   = (u16*)(ws + ((size_t)8 << 20));   // 8 MB  (also reused as x1b)
    u16* Kb   = (u16*)(ws + ((size_t)16 << 20));  // 8 MB
    u16* Vb   = (u16*)(ws + ((size_t)24 << 20));  // 8 MB
    float* x1 = (float*)(ws + ((size_t)32 << 20)); // 16 MB
    float* Fs = (float*)(ws + ((size_t)48 << 20)); // 16 MB (attn_out, later ff)
    u16* hb   = (u16*)(ws + ((size_t)64 << 20));  // 32 MB
    u16* ctxb = xb;
    u16* x1b  = Qb;

    // 1. x -> bf16
    cvt_bf16<<<dim3(NTOK * D_MODEL / 1024), 256, 0, stream>>>(x, xb);

    // 2. QKV projections (Q pre-scaled by 1/sqrt(dk))
    gemm_bt<2><<<dim3(8, 32), 256, 0, stream>>>(xb, Wq, bq, Qb, nullptr,
                                                NTOK, D_MODEL, D_MODEL, 0.125f);
    gemm_bt<2><<<dim3(8, 32), 256, 0, stream>>>(xb, Wk, bk, Kb, nullptr,
                                                NTOK, D_MODEL, D_MODEL, 1.0f);
    gemm_bt<2><<<dim3(8, 32), 256, 0, stream>>>(xb, Wv, bv, Vb, nullptr,
                                                NTOK, D_MODEL, D_MODEL, 1.0f);

    // 3. attention -> ctx (reuses xb)
    attn_fwd<<<dim3(SEQ / 64, 32), 256, 0, stream>>>(Qb, Kb, Vb, ctxb);

    // 4. output projection -> Fs (fp32)
    gemm_bt<0><<<dim3(8, 32), 256, 0, stream>>>(ctxb, Wo, bo, nullptr, Fs,
                                                NTOK, D_MODEL, D_MODEL, 1.0f);

    // 5. x1 = LN(x + attn_out)
    ln_res<<<dim3(NTOK), 256, 0, stream>>>(x, Fs, g1, be1, x1, x1b);

    // 6. h = relu(x1 @ W1^T + b1)
    gemm_bt<1><<<dim3(32, 32), 256, 0, stream>>>(x1b, W1, b1, hb, nullptr,
                                                 NTOK, DFF, D_MODEL, 1.0f);

    // 7. ff = h @ W2^T + b2 -> Fs (fp32)
    gemm_bt<0><<<dim3(8, 32), 256, 0, stream>>>(hb, W2, b2, nullptr, Fs,
                                                NTOK, D_MODEL, DFF, 1.0f);

    // 8. out = LN(x1 + ff)
    ln_res<<<dim3(NTOK), 256, 0, stream>>>(x1, Fs, g2, be2, (float*)d_out, nullptr);
}

// Round 2
// 378.359 us; speedup vs baseline: 1.4112x; 1.4112x over previous
//
#include <hip/hip_runtime.h>

typedef unsigned short u16;
typedef __attribute__((ext_vector_type(8))) short short8;
typedef __attribute__((ext_vector_type(4))) float f32x4;

#define D_MODEL 1024
#define SEQ 2048
#define NH 16
#define DK 64
#define DFF 4096
#define NTOK 4096
#define LOG2E 1.44269504f

__device__ __forceinline__ u16 f2bf(float f) {
    unsigned x = __builtin_bit_cast(unsigned, f);
    x = x + 0x7fffu + ((x >> 16) & 1u);
    return (u16)(x >> 16);
}

__device__ __forceinline__ void gload_lds16(const void* g, void* l) {
    __builtin_amdgcn_global_load_lds(
        (__attribute__((address_space(1))) void*)g,
        (__attribute__((address_space(3))) void*)l, 16, 0, 0);
}

// ---------------- fp32 -> bf16 convert ----------------
__global__ __launch_bounds__(256) void cvt_bf16(const float* __restrict__ in,
                                                u16* __restrict__ out) {
    size_t i = ((size_t)blockIdx.x * 256 + threadIdx.x) * 4;
    float4 v = *(const float4*)(in + i);
    out[i + 0] = f2bf(v.x);
    out[i + 1] = f2bf(v.y);
    out[i + 2] = f2bf(v.z);
    out[i + 3] = f2bf(v.w);
}

// ---------------- GEMM core: acc += A[M,K](bf16) @ W[N,K](bf16)^T, m97-style staging ----------------
template <int BM, int BN>
__device__ __forceinline__ void gemm_acc(const u16* __restrict__ A,
                                         const u16* __restrict__ W,
                                         int K, int m0, int n0,
                                         f32x4 (&acc)[BM / 32][BN / 32]) {
    constexpr int MR = BM / 32, NR = BN / 32;
    __shared__ short8 As[BM][4];
    __shared__ short8 Bs[BN][4];
    const int tid = threadIdx.x;
    const int lane = tid & 63, w = tid >> 6;
    const int l15 = lane & 15, lg = lane >> 4;
    const int wr = (w >> 1) * (BM / 2), wc = (w & 1) * (BN / 2);

#pragma unroll
    for (int i = 0; i < MR; ++i)
#pragma unroll
        for (int j = 0; j < NR; ++j) acc[i][j] = (f32x4){0.f, 0.f, 0.f, 0.f};

    for (int k0 = 0; k0 < K; k0 += 32) {
        __syncthreads();
#pragma unroll
        for (int j = 0; j < BM / 64; ++j) {
            int idx = j * 256 + tid;
            gload_lds16(A + (size_t)(m0 + (idx >> 2)) * K + k0 + (idx & 3) * 8,
                        (char*)As + (j * 256 + w * 64) * 16);
        }
#pragma unroll
        for (int j = 0; j < BN / 64; ++j) {
            int idx = j * 256 + tid;
            gload_lds16(W + (size_t)(n0 + (idx >> 2)) * K + k0 + (idx & 3) * 8,
                        (char*)Bs + (j * 256 + w * 64) * 16);
        }
        __syncthreads();

        short8 af[MR], bf[NR];
#pragma unroll
        for (int m = 0; m < MR; ++m) af[m] = As[wr + m * 16 + l15][lg];
#pragma unroll
        for (int n = 0; n < NR; ++n) bf[n] = Bs[wc + n * 16 + l15][lg];
#pragma unroll
        for (int m = 0; m < MR; ++m)
#pragma unroll
            for (int n = 0; n < NR; ++n)
                acc[m][n] = __builtin_amdgcn_mfma_f32_16x16x32_bf16(
                    af[m], bf[n], acc[m][n], 0, 0, 0);
    }
}

// EPI 0: fp32 out row-major; EPI 1: relu bf16 row-major
template <int BM, int BN, int EPI>
__global__ __launch_bounds__(256) void gemm_bt(
    const u16* __restrict__ A, const u16* __restrict__ W,
    const float* __restrict__ bias, u16* __restrict__ outb,
    float* __restrict__ outf, int M, int N, int K) {
    f32x4 acc[BM / 32][BN / 32];
    const int m0 = blockIdx.y * BM, n0 = blockIdx.x * BN;
    gemm_acc<BM, BN>(A, W, K, m0, n0, acc);
    const int lane = threadIdx.x & 63, w = threadIdx.x >> 6;
    const int l15 = lane & 15, lg = lane >> 4;
    const int wr = (w >> 1) * (BM / 2), wc = (w & 1) * (BN / 2);
#pragma unroll
    for (int m = 0; m < BM / 32; ++m)
#pragma unroll
        for (int n = 0; n < BN / 32; ++n) {
            int gn = n0 + wc + n * 16 + l15;
            float bv = bias[gn];
#pragma unroll
            for (int r = 0; r < 4; ++r) {
                int gm = m0 + wr + m * 16 + lg * 4 + r;
                float v = acc[m][n][r] + bv;
                if (EPI == 0) outf[(size_t)gm * N + gn] = v;
                else outb[(size_t)gm * N + gn] = f2bf(fmaxf(v, 0.f));
            }
        }
}

// fused QKV: one launch, blockIdx.x selects matrix; out in [B,H,S,dk], Q pre-scaled
__global__ __launch_bounds__(256) void gemm_qkv(
    const u16* __restrict__ A, const u16* __restrict__ Wq,
    const u16* __restrict__ Wk, const u16* __restrict__ Wv,
    const float* __restrict__ bq, const float* __restrict__ bk,
    const float* __restrict__ bv, u16* __restrict__ Qo, u16* __restrict__ Ko,
    u16* __restrict__ Vo) {
    const int mat = blockIdx.x >> 3;
    const u16* W = mat == 0 ? Wq : (mat == 1 ? Wk : Wv);
    const float* bias = mat == 0 ? bq : (mat == 1 ? bk : bv);
    u16* out = mat == 0 ? Qo : (mat == 1 ? Ko : Vo);
    const float scale = (mat == 0) ? 0.125f * LOG2E : 1.0f;
    f32x4 acc[4][4];
    const int m0 = blockIdx.y * 128, n0 = (blockIdx.x & 7) * 128;
    gemm_acc<128, 128>(A, W, D_MODEL, m0, n0, acc);
    const int lane = threadIdx.x & 63, w = threadIdx.x >> 6;
    const int l15 = lane & 15, lg = lane >> 4;
    const int wr = (w >> 1) * 64, wc = (w & 1) * 64;
#pragma unroll
    for (int m = 0; m < 4; ++m)
#pragma unroll
        for (int n = 0; n < 4; ++n) {
            int gn = n0 + wc + n * 16 + l15;
            float bv = bias[gn];
            int h = gn >> 6, d = gn & 63;
#pragma unroll
            for (int r = 0; r < 4; ++r) {
                int gm = m0 + wr + m * 16 + lg * 4 + r;
                int b = gm >> 11, s = gm & 2047;
                float v = (acc[m][n][r] + bv) * scale;
                out[(((size_t)(b * NH + h)) * SEQ + s) * DK + d] = f2bf(v);
            }
        }
}

// ---------------- flash attention, KVBLK=64, defer-max, exp2 domain ----------------
__global__ __launch_bounds__(256) void attn_fwd(const u16* __restrict__ Q,
                                                const u16* __restrict__ Kp,
                                                const u16* __restrict__ V,
                                                u16* __restrict__ ctx) {
    __shared__ __align__(16) u16 Vt[64 * 72];       // [d][t], stride 72
    __shared__ __align__(16) u16 Ps[4][16 * 72];    // per-wave [q][t], stride 72

    const int tid = threadIdx.x;
    const int lane = tid & 63;
    const int w = tid >> 6;
    const int l15 = lane & 15;
    const int lg = lane >> 4;
    const int bh = blockIdx.y;
    const int qbase = blockIdx.x * 64 + w * 16;
    const size_t base = (size_t)bh * SEQ * DK;
    const u16* Qb = Q + base;
    const u16* Kb = Kp + base;
    const u16* Vb = V + base;

    short8 qf[2];
#pragma unroll
    for (int hf = 0; hf < 2; ++hf)
        qf[hf] = *(const short8*)(Qb + (size_t)(qbase + l15) * DK + hf * 32 + lg * 8);

    f32x4 zero = {0.f, 0.f, 0.f, 0.f};
    f32x4 o[4];
#pragma unroll
    for (int db = 0; db < 4; ++db) o[db] = zero;
    float mrun[4], lrun[4];
#pragma unroll
    for (int r = 0; r < 4; ++r) { mrun[r] = -1e30f; lrun[r] = 0.f; }

    const int vt = tid & 63, vdg = tid >> 6;
    u16* Pu = Ps[w];

    for (int t0 = 0; t0 < SEQ; t0 += 64) {
        __syncthreads();
        {   // stage V^T (each thread: 2 short8 loads, 16 scalar transposed writes)
            short8 v0 = *(const short8*)(Vb + (size_t)(t0 + vt) * DK + vdg * 8);
            short8 v1 = *(const short8*)(Vb + (size_t)(t0 + vt) * DK + 32 + vdg * 8);
#pragma unroll
            for (int j = 0; j < 8; ++j) {
                Vt[(vdg * 8 + j) * 72 + vt] = (u16)v0[j];
                Vt[(32 + vdg * 8 + j) * 72 + vt] = (u16)v1[j];
            }
        }
        __syncthreads();

        // scores: 4 nb blocks of 16 kv
        f32x4 sc[4];
#pragma unroll
        for (int nb = 0; nb < 4; ++nb) {
            short8 kf0 = *(const short8*)(Kb + (size_t)(t0 + nb * 16 + l15) * DK + lg * 8);
            short8 kf1 = *(const short8*)(Kb + (size_t)(t0 + nb * 16 + l15) * DK + 32 + lg * 8);
            sc[nb] = __builtin_amdgcn_mfma_f32_16x16x32_bf16(qf[0], kf0, zero, 0, 0, 0);
            sc[nb] = __builtin_amdgcn_mfma_f32_16x16x32_bf16(qf[1], kf1, sc[nb], 0, 0, 0);
        }

        // defer-max: only reduce + rescale when local max exceeds m+8
        float lm[4];
        float need = 0.f;
#pragma unroll
        for (int r = 0; r < 4; ++r) {
            lm[r] = fmaxf(fmaxf(sc[0][r], sc[1][r]), fmaxf(sc[2][r], sc[3][r]));
            need = fmaxf(need, lm[r] - mrun[r]);
        }
        if (__any(need > 8.f)) {
#pragma unroll
            for (int r = 0; r < 4; ++r) {
                float rv = lm[r];
#pragma unroll
                for (int off = 8; off; off >>= 1) rv = fmaxf(rv, __shfl_xor(rv, off));
                float mnew = fmaxf(mrun[r], rv);
                float fac = exp2f(mrun[r] - mnew);
                lrun[r] *= fac;
#pragma unroll
                for (int db = 0; db < 4; ++db) o[db][r] *= fac;
                mrun[r] = mnew;
            }
        }

        // P = exp2(sc - m), store bf16, accumulate per-lane partial row sums
#pragma unroll
        for (int r = 0; r < 4; ++r) {
            const int q = lg * 4 + r;
            float s = 0.f;
#pragma unroll
            for (int nb = 0; nb < 4; ++nb) {
                float p = exp2f(sc[nb][r] - mrun[r]);
                s += p;
                Pu[q * 72 + nb * 16 + l15] = f2bf(p);
            }
            lrun[r] += s;
        }

        // PV
        short8 pa0 = *(const short8*)(Pu + l15 * 72 + lg * 8);
        short8 pa1 = *(const short8*)(Pu + l15 * 72 + 32 + lg * 8);
#pragma unroll
        for (int db = 0; db < 4; ++db) {
            short8 vb0 = *(const short8*)(Vt + (db * 16 + l15) * 72 + lg * 8);
            short8 vb1 = *(const short8*)(Vt + (db * 16 + l15) * 72 + 32 + lg * 8);
            o[db] = __builtin_amdgcn_mfma_f32_16x16x32_bf16(pa0, vb0, o[db], 0, 0, 0);
            o[db] = __builtin_amdgcn_mfma_f32_16x16x32_bf16(pa1, vb1, o[db], 0, 0, 0);
        }
    }

    const int b = bh >> 4, h = bh & 15;
#pragma unroll
    for (int r = 0; r < 4; ++r) {
        float s = lrun[r];
#pragma unroll
        for (int off = 8; off; off >>= 1) s += __shfl_xor(s, off);
        float inv = 1.0f / s;
        int srow = qbase + lg * 4 + r;
        size_t rowoff = ((size_t)(b * SEQ + srow)) * D_MODEL + h * DK;
#pragma unroll
        for (int db = 0; db < 4; ++db)
            ctx[rowoff + db * 16 + l15] = f2bf(o[db][r] * inv);
    }
}

// ---------------- fused residual + LayerNorm ----------------
__global__ __launch_bounds__(256) void ln_res(const float* __restrict__ X,
                                              const float* __restrict__ Y,
                                              const float* __restrict__ gamma,
                                              const float* __restrict__ beta,
                                              float* __restrict__ outf,
                                              u16* __restrict__ outb) {
    __shared__ float red[8];
    const int row = blockIdx.x, t = threadIdx.x;
    const size_t off = (size_t)row * D_MODEL + t * 4;
    float4 xv = *(const float4*)(X + off);
    float4 yv = *(const float4*)(Y + off);
    float sx = xv.x + yv.x, sy = xv.y + yv.y, sz = xv.z + yv.z, sw = xv.w + yv.w;
    float ps = sx + sy + sz + sw;
#pragma unroll
    for (int o2 = 32; o2; o2 >>= 1) ps += __shfl_xor(ps, o2);
    if ((t & 63) == 0) red[t >> 6] = ps;
    __syncthreads();
    float mu = (red[0] + red[1] + red[2] + red[3]) * (1.0f / D_MODEL);
    float d0 = sx - mu, d1 = sy - mu, d2 = sz - mu, d3 = sw - mu;
    float p2 = d0 * d0 + d1 * d1 + d2 * d2 + d3 * d3;
#pragma unroll
    for (int o2 = 32; o2; o2 >>= 1) p2 += __shfl_xor(p2, o2);
    if ((t & 63) == 0) red[4 + (t >> 6)] = p2;
    __syncthreads();
    float var = (red[4] + red[5] + red[6] + red[7]) * (1.0f / D_MODEL);
    float rstd = rsqrtf(var + 1e-5f);
    float4 gv = *(const float4*)(gamma + t * 4);
    float4 bv = *(const float4*)(beta + t * 4);
    float r0 = d0 * rstd * gv.x + bv.x;
    float r1 = d1 * rstd * gv.y + bv.y;
    float r2 = d2 * rstd * gv.z + bv.z;
    float r3 = d3 * rstd * gv.w + bv.w;
    float4 res; res.x = r0; res.y = r1; res.z = r2; res.w = r3;
    *(float4*)(outf + off) = res;
    if (outb) {
        outb[off + 0] = f2bf(r0);
        outb[off + 1] = f2bf(r1);
        outb[off + 2] = f2bf(r2);
        outb[off + 3] = f2bf(r3);
    }
}

extern "C" void kernel_launch(void* const* d_in, const int* in_sizes, int n_in,
                              void* d_out, int out_size, void* d_ws, size_t ws_size,
                              hipStream_t stream) {
    (void)in_sizes; (void)n_in; (void)out_size; (void)ws_size;
    const float* x  = (const float*)d_in[0];
    const float* Wq = (const float*)d_in[1];
    const float* bq = (const float*)d_in[2];
    const float* Wk = (const float*)d_in[3];
    const float* bk = (const float*)d_in[4];
    const float* Wv = (const float*)d_in[5];
    const float* bv = (const float*)d_in[6];
    const float* Wo = (const float*)d_in[7];
    const float* bo = (const float*)d_in[8];
    const float* W1 = (const float*)d_in[9];
    const float* b1 = (const float*)d_in[10];
    const float* W2 = (const float*)d_in[11];
    const float* b2 = (const float*)d_in[12];
    const float* g1 = (const float*)d_in[13];
    const float* be1 = (const float*)d_in[14];
    const float* g2 = (const float*)d_in[15];
    const float* be2 = (const float*)d_in[16];

    char* ws = (char*)d_ws;                         // 96 MB total, carefully overlapped
    u16* xb   = (u16*)(ws);                         // 8 MB : x bf16, then ctx
    u16* Qb   = (u16*)(ws + ((size_t)8 << 20));     // 8 MB : Q, then W1b (after attn)
    u16* Kb   = (u16*)(ws + ((size_t)16 << 20));    // 8 MB : K, then W2b (after attn)
    u16* Vb   = (u16*)(ws + ((size_t)24 << 20));    // 8 MB : V, then x1b
    float* x1 = (float*)(ws + ((size_t)32 << 20));  // 16 MB
    float* Fs = (float*)(ws + ((size_t)48 << 20));  // 16 MB : attn_out, later ff
    u16* hb   = (u16*)(ws + ((size_t)64 << 20));    // 32 MB : Wq/Wk/Wv/Wo bf16, then h
    u16* Wqb = hb;
    u16* Wkb = hb + (1u << 20);
    u16* Wvb = hb + (2u << 20);
    u16* Wob = hb + (3u << 20);
    u16* W1b = Qb;
    u16* W2b = Kb;
    u16* ctxb = xb;
    u16* x1b  = Vb;

    // 1. convert x and the 4 d*d weights to bf16
    cvt_bf16<<<dim3(NTOK * D_MODEL / 1024), 256, 0, stream>>>(x, xb);
    cvt_bf16<<<dim3(1024), 256, 0, stream>>>(Wq, Wqb);
    cvt_bf16<<<dim3(1024), 256, 0, stream>>>(Wk, Wkb);
    cvt_bf16<<<dim3(1024), 256, 0, stream>>>(Wv, Wvb);
    cvt_bf16<<<dim3(1024), 256, 0, stream>>>(Wo, Wob);

    // 2. fused QKV projections (Q pre-scaled by 1/sqrt(dk) * log2e)
    gemm_qkv<<<dim3(24, 32), 256, 0, stream>>>(xb, Wqb, Wkb, Wvb, bq, bk, bv,
                                               Qb, Kb, Vb);

    // 3. attention -> ctx (reuses xb)
    attn_fwd<<<dim3(SEQ / 64, 32), 256, 0, stream>>>(Qb, Kb, Vb, ctxb);

    // 4. convert FFN weights into now-dead Q/K slots
    cvt_bf16<<<dim3(4096), 256, 0, stream>>>(W1, W1b);
    cvt_bf16<<<dim3(4096), 256, 0, stream>>>(W2, W2b);

    // 5. output projection -> Fs (fp32)
    gemm_bt<64, 128, 0><<<dim3(8, 64), 256, 0, stream>>>(
        ctxb, Wob, bo, nullptr, Fs, NTOK, D_MODEL, D_MODEL);

    // 6. x1 = LN(x + attn_out)
    ln_res<<<dim3(NTOK), 256, 0, stream>>>(x, Fs, g1, be1, x1, x1b);

    // 7. h = relu(x1 @ W1^T + b1)
    gemm_bt<128, 128, 1><<<dim3(32, 32), 256, 0, stream>>>(
        x1b, W1b, b1, hb, nullptr, NTOK, DFF, D_MODEL);

    // 8. ff = h @ W2^T + b2 -> Fs (fp32)
    gemm_bt<64, 128, 0><<<dim3(8, 64), 256, 0, stream>>>(
        hb, W2b, b2, nullptr, Fs, NTOK, D_MODEL, DFF);

    // 9. out = LN(x1 + ff)
    ln_res<<<dim3(NTOK), 256, 0, stream>>>(x1, Fs, g2, be2, (float*)d_out, nullptr);
}